// Round 6
// baseline (464.876 us; speedup 1.0000x reference)
//
#include <hip/hip_runtime.h>
#include <math.h>

namespace {

typedef _Float16 half8v __attribute__((ext_vector_type(8)));
typedef _Float16 half4v __attribute__((ext_vector_type(4)));
typedef float    floatx4 __attribute__((ext_vector_type(4)));

constexpr int B   = 8;
constexpr int C   = 256;
constexpr int NH  = 4;
constexpr int HD  = 64;
constexpr int NWIN = 400;   // 20x20 windows per level
constexpr int NT  = 35;     // 25 + 9 + 1 tokens per window
constexpr int QKVN = 768;
constexpr int RPB = NWIN * NT;  // 14,000 token-rows per batch

// per-batch byte counts for workspace
constexpr size_t QKV_B  = (size_t)8400 * QKVN * 2;   // 12,902,400  (f16)
constexpr size_t OATT_B = (size_t)RPB * C * 2;       //  7,168,000  (f16)
constexpr size_t YT_B   = (size_t)RPB * C * 4;       // 14,336,000  (f32)
constexpr size_t PB_B   = QKV_B + OATT_B + YT_B;     // 34,406,400
constexpr size_t XT_B   = (size_t)8400 * C * 2;      //  4,300,800  (f16 transposed X)
constexpr size_t WT_B   = (size_t)3 * QKVN * C * 2;  //  1,179,648  (f16 transposed W)
constexpr size_t POS_B  = 19712;                     // 4900 f32, padded

// ---------------- pos table ----------------
__device__ inline void token_coord(int j, double& cy, double& cx) {
  if (j < 25)      { int ty = j / 5,  tx = j % 5;  cy = (double)(ty - 2); cx = (double)(tx - 2); }
  else if (j < 34) { int t = j - 25; int ty = t / 3, tx = t % 3;
                     cy = (double)(ty - 1) * (5.0 / 3.0); cx = (double)(tx - 1) * (5.0 / 3.0); }
  else             { cy = 0.0; cx = 0.0; }
}

__global__ void pos_kernel(const float* __restrict__ rpb, const float* __restrict__ ab,
                           float* __restrict__ pos) {
  int p = blockIdx.x * blockDim.x + threadIdx.x;
  if (p >= NH * NT * NT) return;
  int j = p % NT, i = (p / NT) % NT, h = p / (NT * NT);
  double cyi, cxi, cyj, cxj;
  token_coord(i, cyi, cxi);
  token_coord(j, cyj, cxj);
  float fidx = (float)(((cyi - cyj) + 4.0) * 9.0 + ((cxi - cxj) + 4.0));
  int fl = min(max((int)floorf(fidx), 0), 80);
  int ce = min(max((int)ceilf(fidx), 0), 80);
  float w = fidx - (float)fl;
  float pv = (1.0f - w) * rpb[fl * NH + h] + w * rpb[ce * NH + h];
  int li = (i < 25) ? 0 : ((i < 34) ? 1 : 2);
  pos[p] = pv + ab[li * NH + h];
}

// ---------------- fused transpose: [C=256][HWi] f32 -> [M][256] f16 row-major ----------------
// Handles Xt0/Xt1/Xt2 (per batch-group) and Wt0..2 (W is [256][768] -> Wt [768][256]).
// Tile: 64 output rows x 256 channels via LDS.
__global__ __launch_bounds__(256) void xpose_kernel(const float* __restrict__ x0,
                                                    const float* __restrict__ x1,
                                                    const float* __restrict__ x2,
                                                    const float* __restrict__ w0,
                                                    const float* __restrict__ w1,
                                                    const float* __restrict__ w2,
                                                    _Float16* __restrict__ xt0,
                                                    _Float16* __restrict__ xt1,
                                                    _Float16* __restrict__ xt2,
                                                    _Float16* __restrict__ wt,
                                                    int c0, int c1, int c2, int c3, int c4,
                                                    int g) {
  int bx = blockIdx.x;
  const float* src; _Float16* dst; int HWi, Mg, m0;
  if (bx < c0)      { src = x0; dst = xt0; HWi = 6400; Mg = g * 6400; m0 = bx * 64; }
  else if (bx < c1) { src = x1; dst = xt1; HWi = 1600; Mg = g * 1600; m0 = (bx - c0) * 64; }
  else if (bx < c2) { src = x2; dst = xt2; HWi = 400;  Mg = g * 400;  m0 = (bx - c1) * 64; }
  else if (bx < c3) { src = w0; dst = wt;                HWi = 768; Mg = 768; m0 = (bx - c2) * 64; }
  else if (bx < c4) { src = w1; dst = wt + 768 * 256;    HWi = 768; Mg = 768; m0 = (bx - c3) * 64; }
  else              { src = w2; dst = wt + 2 * 768 * 256; HWi = 768; Mg = 768; m0 = (bx - c4) * 64; }

  __shared__ _Float16 t[64][257];
  const int tid = threadIdx.x;

  // read: 16 iterations x (16 channels x 64 pixels); float4 along pixels (coalesced)
  const int p4 = (tid & 15) * 4;          // pixel-in-tile base for this thread
#pragma unroll
  for (int it = 0; it < 16; ++it) {
    int c = it * 16 + (tid >> 4);
    int pg = m0 + p4;
    int pgc = min(pg, Mg - 4);            // clamp (Mg always multiple of 4); bad rows skipped on write
    int bb = pgc / HWi, pix = pgc - bb * HWi;
    floatx4 v = *(const floatx4*)(src + ((size_t)bb * C + c) * HWi + pix);
#pragma unroll
    for (int i = 0; i < 4; ++i) t[p4 + i][c] = (_Float16)v[i];
  }
  __syncthreads();

  // write: 8 iterations x (32 rows-worth of half8 chunks); coalesced along channels
#pragma unroll
  for (int e0 = 0; e0 < 8; ++e0) {
    int e = e0 * 256 + tid;
    int p = e >> 5, c8 = e & 31;
    if (m0 + p < Mg)
      *(half8v*)(dst + (size_t)(m0 + p) * C + c8 * 8) = *(const half8v*)&t[p][c8 * 8];
  }
}

// ---------------- fused QKV GEMM (f16 MFMA, 128x128 tile, all 3 levels, reg-prefetch) ----------
// A = Xt (f16 [Mg][256] row-major), B = Wt (f16 [768][256] row-major, i.e. N-major).
// Staging is pure contiguous b128 copies (2 A + 2 B loads per lane per K-step).
// Epilogue: L2-normalize each output row per 64-col head section when n0 < 512 (q,k).
__global__ __launch_bounds__(256) void qkv_gemm(const _Float16* __restrict__ Xt0,
                                                const _Float16* __restrict__ Xt1,
                                                const _Float16* __restrict__ Xt2,
                                                const _Float16* __restrict__ Wt,
                                                _Float16* __restrict__ Y0,
                                                _Float16* __restrict__ Y1,
                                                _Float16* __restrict__ Y2,
                                                int mb0, int mb01, int g) {
  __shared__ _Float16 As[128][40];   // row 80B, 16B-aligned frag reads
  __shared__ _Float16 Bs[128][40];

  int mblk = blockIdx.x;
  const _Float16* Xt; const _Float16* WtL; _Float16* Y; int Mg;
  if (mblk < mb0)       { Xt = Xt0; WtL = Wt;                Y = Y0; Mg = g * 6400; }
  else if (mblk < mb01) { Xt = Xt1; WtL = Wt + 768 * 256;    Y = Y1; Mg = g * 1600; mblk -= mb0; }
  else                  { Xt = Xt2; WtL = Wt + 2 * 768 * 256; Y = Y2; Mg = g * 400;  mblk -= mb01; }

  const int tid  = threadIdx.x;
  const int m0   = mblk * 128;
  const int n0   = blockIdx.y * 128;
  const int w    = tid >> 6;
  const int lane = tid & 63;
  const int quad = lane >> 4;
  const int mn   = lane & 15;

  // staging geometry (k-invariant): 512 units = 128 rows x 4 k-octs
  int rr[2], k8[2];
  size_t aOff[2], bOff[2];
#pragma unroll
  for (int u = 0; u < 2; ++u) {
    int e = u * 256 + tid;
    rr[u] = e >> 2; k8[u] = e & 3;
    aOff[u] = (size_t)min(m0 + rr[u], Mg - 1) * C + k8[u] * 8;
    bOff[u] = (size_t)(n0 + rr[u]) * C + k8[u] * 8;
  }

  half8v apre[2], bpre[2];
  auto PLOAD = [&](int k0) {
#pragma unroll
    for (int u = 0; u < 2; ++u) {
      apre[u] = *(const half8v*)(Xt + aOff[u] + k0);
      bpre[u] = *(const half8v*)(WtL + bOff[u] + k0);
    }
  };

  PLOAD(0);
  floatx4 acc[2][8] = {};
  for (int k0 = 0; k0 < C; k0 += 32) {
#pragma unroll
    for (int u = 0; u < 2; ++u) {
      *(half8v*)&As[rr[u]][k8[u] * 8] = apre[u];
      *(half8v*)&Bs[rr[u]][k8[u] * 8] = bpre[u];
    }
    __syncthreads();
    if (k0 + 32 < C) PLOAD(k0 + 32);   // prefetch next K-step under MFMA
    half8v a0 = *(const half8v*)&As[w * 32 + mn][quad * 8];
    half8v a1 = *(const half8v*)&As[w * 32 + 16 + mn][quad * 8];
#pragma unroll
    for (int ni = 0; ni < 8; ++ni) {
      half8v bf = *(const half8v*)&Bs[ni * 16 + mn][quad * 8];
      acc[0][ni] = __builtin_amdgcn_mfma_f32_16x16x32_f16(a0, bf, acc[0][ni], 0, 0, 0);
      acc[1][ni] = __builtin_amdgcn_mfma_f32_16x16x32_f16(a1, bf, acc[1][ni], 0, 0, 0);
    }
    __syncthreads();
  }

  // epilogue: per-row L2 norm per 64-col head section (two sections per 128-tile)
  const bool do_norm = (n0 < 512);
#pragma unroll
  for (int mi = 0; mi < 2; ++mi) {
#pragma unroll
    for (int r = 0; r < 4; ++r) {
      float s0 = 0.f, s1 = 0.f;
#pragma unroll
      for (int ni = 0; ni < 4; ++ni) { float vv = acc[mi][ni][r]; s0 += vv * vv; }
#pragma unroll
      for (int ni = 4; ni < 8; ++ni) { float vv = acc[mi][ni][r]; s1 += vv * vv; }
      s0 += __shfl_xor(s0, 1); s1 += __shfl_xor(s1, 1);
      s0 += __shfl_xor(s0, 2); s1 += __shfl_xor(s1, 2);
      s0 += __shfl_xor(s0, 4); s1 += __shfl_xor(s1, 4);
      s0 += __shfl_xor(s0, 8); s1 += __shfl_xor(s1, 8);
      float sc0 = do_norm ? (1.f / fmaxf(sqrtf(s0), 1e-12f)) : 1.f;
      float sc1 = do_norm ? (1.f / fmaxf(sqrtf(s1), 1e-12f)) : 1.f;
      int row = m0 + w * 32 + mi * 16 + quad * 4 + r;
      if (row < Mg) {
#pragma unroll
        for (int ni = 0; ni < 8; ++ni)
          Y[(size_t)row * QKVN + n0 + ni * 16 + mn] =
              (_Float16)(acc[mi][ni][r] * (ni < 4 ? sc0 : sc1));
      }
    }
  }
}

// ---------------- attention: swapped-operand MFMA version. Block = (b, window); wave = head. ----------------
__device__ inline const _Float16* token_row_ptr(int j, int wy, int wx, int b,
                                                const _Float16* q0, const _Float16* q1,
                                                const _Float16* q2) {
  if (j >= NT) return nullptr;
  int k_, s_, p_, Hl, t; const _Float16* base;
  if (j < 25)      { k_ = 5; s_ = 4; p_ = 2; Hl = 80; t = j;      base = q0; }
  else if (j < 34) { k_ = 3; s_ = 2; p_ = 1; Hl = 40; t = j - 25; base = q1; }
  else             { k_ = 1; s_ = 1; p_ = 0; Hl = 20; t = 0;      base = q2; }
  int ty = t / k_, tx = t % k_;
  int y = wy * s_ + ty - p_;
  int x = wx * s_ + tx - p_;
  if ((unsigned)y >= (unsigned)Hl || (unsigned)x >= (unsigned)Hl) return nullptr;
  return base + ((size_t)b * Hl * Hl + (size_t)y * Hl + x) * QKVN;
}

__global__ __launch_bounds__(256, 4) void attn_kernel(const _Float16* __restrict__ qkv0,
                                                      const _Float16* __restrict__ qkv1,
                                                      const _Float16* __restrict__ qkv2,
                                                      const float* __restrict__ pos,
                                                      _Float16* __restrict__ O) {
  const int blk = blockIdx.x;               // b*NWIN + w
  const int w   = blk % NWIN;
  const int b   = blk / NWIN;
  const int wy = w / 20, wx = w % 20;
  const int tid  = threadIdx.x;
  const int h    = tid >> 6;                // wave = head
  const int lane = tid & 63;
  const int i16  = lane & 15;
  const int q4   = lane >> 4;

  __shared__ __align__(16) _Float16 vrows[48][260];   // V row-major, all heads; rows 35..47 zero

  // --- cooperative V staging: 1536 half8-chunks = 48 rows x 32 chunks over 256 threads
#pragma unroll
  for (int e0 = 0; e0 < 1536; e0 += 256) {
    int e = e0 + tid;
    int j = e >> 5, cc = e & 31;
    half8v val = (half8v)(_Float16)0.f;
    if (j < NT) {
      const _Float16* rp = token_row_ptr(j, wy, wx, b, qkv0, qkv1, qkv2);
      if (rp) val = *(const half8v*)(rp + 512 + cc * 8);
    }
    *(half8v*)&vrows[j][cc * 8] = val;
  }

  // --- Q/K fragments direct from global: tile t rows = tokens t*16 + i16
  half8v qf[3][2], kf[3][2];
#pragma unroll
  for (int t = 0; t < 3; ++t) {
    const _Float16* rp = token_row_ptr(t * 16 + i16, wy, wx, b, qkv0, qkv1, qkv2);
#pragma unroll
    for (int kc = 0; kc < 2; ++kc) {
      if (rp) {
        qf[t][kc] = *(const half8v*)(rp + h * HD + kc * 32 + q4 * 8);
        kf[t][kc] = *(const half8v*)(rp + 256 + h * HD + kc * 32 + q4 * 8);
      } else {
        qf[t][kc] = (half8v)(_Float16)0.f;
        kf[t][kc] = (half8v)(_Float16)0.f;
      }
    }
  }

  // --- swapped QK^T: s[tj][ti][r] = S^T[j=tj*16+q4*4+r][i=ti*16+i16]
  floatx4 s[3][3] = {};
#pragma unroll
  for (int kc = 0; kc < 2; ++kc)
#pragma unroll
    for (int tj = 0; tj < 3; ++tj)
#pragma unroll
      for (int ti = 0; ti < 3; ++ti)
        s[tj][ti] = __builtin_amdgcn_mfma_f32_16x16x32_f16(kf[tj][kc], qf[ti][kc], s[tj][ti], 0, 0, 0);

  // --- pos bias + tile-pad mask (j >= NT -> -inf; tj=0 rows are never masked so max stays finite)
#pragma unroll
  for (int tj = 0; tj < 3; ++tj)
#pragma unroll
    for (int ti = 0; ti < 3; ++ti)
#pragma unroll
      for (int r = 0; r < 4; ++r) {
        int j = tj * 16 + q4 * 4 + r;
        int i = ti * 16 + i16;
        if (j < NT) { if (i < NT) s[tj][ti][r] += pos[(h * NT + i) * NT + j]; }
        else s[tj][ti][r] = -INFINITY;
      }

  // --- in-register softmax over j per query i (col i16): 12 local regs + shfl_xor 16/32
  half4v pa[3][3];   // [tj][ti] = A-frag of P for PV (16x16x16 layout)
#pragma unroll
  for (int ti = 0; ti < 3; ++ti) {
    float m = s[0][ti][0];
#pragma unroll
    for (int tj = 0; tj < 3; ++tj)
#pragma unroll
      for (int r = 0; r < 4; ++r) m = fmaxf(m, s[tj][ti][r]);
    m = fmaxf(m, __shfl_xor(m, 16));
    m = fmaxf(m, __shfl_xor(m, 32));
    float sum = 0.f;
#pragma unroll
    for (int tj = 0; tj < 3; ++tj)
#pragma unroll
      for (int r = 0; r < 4; ++r) { float e = expf(s[tj][ti][r] - m); s[tj][ti][r] = e; sum += e; }
    sum += __shfl_xor(sum, 16);
    sum += __shfl_xor(sum, 32);
    float inv = 1.f / sum;
#pragma unroll
    for (int tj = 0; tj < 3; ++tj)
#pragma unroll
      for (int r = 0; r < 4; ++r) pa[tj][ti][r] = (_Float16)(s[tj][ti][r] * inv);
  }

  __syncthreads();   // vrows ready for all waves

  // --- V B-frags for 16x16x16: lane holds V[j=tj*16+q4*4+kk][d=n*16+i16] (this head's cols)
  half4v vb[3][4];
#pragma unroll
  for (int tj = 0; tj < 3; ++tj)
#pragma unroll
    for (int n = 0; n < 4; ++n)
#pragma unroll
      for (int kk = 0; kk < 4; ++kk)
        vb[tj][n][kk] = vrows[tj * 16 + q4 * 4 + kk][h * HD + n * 16 + i16];

  // --- PV: O[i][d] accumulated over 3 j-chunks of 16; C layout row=q4*4+r (i), col=i16 (d)
  const size_t obase = ((size_t)(b * NWIN + w) * NT) * C + h * HD;
#pragma unroll
  for (int ti = 0; ti < 3; ++ti) {
    floatx4 o[4] = {};
#pragma unroll
    for (int tj = 0; tj < 3; ++tj)
#pragma unroll
      for (int n = 0; n < 4; ++n)
        o[n] = __builtin_amdgcn_mfma_f32_16x16x16f16(pa[tj][ti], vb[tj][n], o[n], 0, 0, 0);
#pragma unroll
    for (int r = 0; r < 4; ++r) {
      int i = ti * 16 + q4 * 4 + r;
      if (i < NT) {
#pragma unroll
        for (int n = 0; n < 4; ++n)
          O[obase + (size_t)i * C + n * 16 + i16] = (_Float16)o[n][r];
      }
    }
  }
}

// ---------------- proj GEMM (f16 MFMA, reg-prefetch) + bias, transposed store ----------------
__global__ __launch_bounds__(256) void proj_gemm(const _Float16* __restrict__ A,  // (Mg, 256) f16 row-major
                                                 const float* __restrict__ W,     // (256, 256) row-major
                                                 const float* __restrict__ bias,
                                                 float* __restrict__ Yt, int Mg) {
  __shared__ __align__(16) char smem[128 * 69 * 4];   // max(As+Bs = 15360, Cs = 35328)
  _Float16 (*As)[40] = (_Float16(*)[40])smem;
  _Float16 (*Bs)[40] = (_Float16(*)[40])(smem + 128 * 40 * 2);
  float    (*Cs)[69] = (float(*)[69])smem;

  const int tid  = threadIdx.x;
  const int m0   = blockIdx.x * 128;
  const int n0   = blockIdx.y * 64;
  const int w    = tid >> 6;
  const int lane = tid & 63;
  const int quad = lane >> 4;
  const int mn   = lane & 15;

  int aM[2], aK8[2], aRow[2];
#pragma unroll
  for (int u = 0; u < 2; ++u) {
    int e = u * 256 + tid;           // 512 units: 128 m x 4 k-octs
    aM[u] = e >> 2; aK8[u] = e & 3;
    aRow[u] = min(m0 + aM[u], Mg - 1);
  }

  half8v apre[2]; float bpre[8];
  auto PLOAD = [&](int k0) {
#pragma unroll
    for (int u = 0; u < 2; ++u)
      apre[u] = *(const half8v*)&A[(size_t)aRow[u] * C + k0 + 8 * aK8[u]];
    const float* wp = W + (size_t)(k0 + w * 8) * C + n0 + lane;
#pragma unroll
    for (int j = 0; j < 8; ++j) bpre[j] = wp[(size_t)j * C];
  };

  PLOAD(0);
  floatx4 acc[2][4] = {};
  for (int k0 = 0; k0 < C; k0 += 32) {
#pragma unroll
    for (int u = 0; u < 2; ++u) *(half8v*)&As[aM[u]][8 * aK8[u]] = apre[u];
    {
      half8v hv;
#pragma unroll
      for (int j = 0; j < 8; ++j) hv[j] = (_Float16)bpre[j];
      *(half8v*)&Bs[lane][w * 8] = hv;
    }
    __syncthreads();
    if (k0 + 32 < C) PLOAD(k0 + 32);   // prefetch next K-step under MFMA
    half8v a0 = *(const half8v*)&As[w * 32 + mn][quad * 8];
    half8v a1 = *(const half8v*)&As[w * 32 + 16 + mn][quad * 8];
#pragma unroll
    for (int ni = 0; ni < 4; ++ni) {
      half8v bf = *(const half8v*)&Bs[ni * 16 + mn][quad * 8];
      acc[0][ni] = __builtin_amdgcn_mfma_f32_16x16x32_f16(a0, bf, acc[0][ni], 0, 0, 0);
      acc[1][ni] = __builtin_amdgcn_mfma_f32_16x16x32_f16(a1, bf, acc[1][ni], 0, 0, 0);
    }
    __syncthreads();   // also protects As/Bs before Cs aliasing overwrite
  }

  // epilogue: bias add into Cs, then transposed coalesced store
#pragma unroll
  for (int mi = 0; mi < 2; ++mi)
#pragma unroll
    for (int r = 0; r < 4; ++r)
#pragma unroll
      for (int ni = 0; ni < 4; ++ni)
        Cs[w * 32 + mi * 16 + quad * 4 + r][ni * 16 + mn] =
            acc[mi][ni][r] + bias[n0 + ni * 16 + mn];
  __syncthreads();
#pragma unroll
  for (int u = 0; u < 32; ++u) {
    int e = u * 256 + tid;            // 8192 elems: 128 m x 64 n
    int ml = e & 127, cl = e >> 7;
    int m = m0 + ml;
    if (m < Mg) {
      int bb = m / RPB;
      int r = m - bb * RPB;
      Yt[((size_t)bb * C + n0 + cl) * RPB + r] = Cs[ml][cl];
    }
  }
}

// ---------------- fold (gather form), group-local ----------------
__global__ __launch_bounds__(256) void fold_kernel(const float* __restrict__ Yt,
                                                   float* __restrict__ out,
                                                   int k_, int s_, int p_, int H_,
                                                   int toff, int total) {
  int idx = blockIdx.x * 256 + threadIdx.x;
  if (idx >= total) return;
  int x = idx % H_;
  int y = (idx / H_) % H_;
  int c = (idx / (H_ * H_)) % C;
  int b = idx / (C * H_ * H_);
  int py = y + p_, px = x + p_;
  int ay = py - k_ + 1;
  int wy_lo = ay <= 0 ? 0 : (ay + s_ - 1) / s_;
  int wy_hi = min(19, py / s_);
  int ax = px - k_ + 1;
  int wx_lo = ax <= 0 ? 0 : (ax + s_ - 1) / s_;
  int wx_hi = min(19, px / s_);
  const float* base = Yt + ((size_t)b * C + c) * RPB;
  float acc = 0.f;
  for (int wy = wy_lo; wy <= wy_hi; ++wy) {
    int tyy = py - wy * s_;
    for (int wx = wx_lo; wx <= wx_hi; ++wx) {
      int txx = px - wx * s_;
      acc += base[(wy * 20 + wx) * NT + toff + tyy * k_ + txx];
    }
  }
  out[idx] = acc;
}

} // namespace

extern "C" void kernel_launch(void* const* d_in, const int* in_sizes, int n_in,
                              void* d_out, int out_size, void* d_ws, size_t ws_size,
                              hipStream_t stream) {
  const float* x0    = (const float*)d_in[0];
  const float* x1    = (const float*)d_in[1];
  const float* x2    = (const float*)d_in[2];
  const float* wq0   = (const float*)d_in[3];
  const float* wq1   = (const float*)d_in[4];
  const float* wq2   = (const float*)d_in[5];
  const float* wproj = (const float*)d_in[6];
  const float* bproj = (const float*)d_in[7];
  const float* rpb   = (const float*)d_in[8];
  const float* ab    = (const float*)d_in[9];
  float* out = (float*)d_out;

  // pick largest batch-group size g in {8,4,2,1} that fits ws_size (incl. Xt/Wt buffers)
  int g = 8;
  while (g > 1 && POS_B + (size_t)g * (PB_B + XT_B) + WT_B > ws_size) g >>= 1;

  char* ws = (char*)d_ws;
  float*    posb  = (float*)ws;
  _Float16* qkv0g = (_Float16*)(ws + POS_B);
  _Float16* qkv1g = qkv0g + (size_t)g * 6400 * QKVN;
  _Float16* qkv2g = qkv1g + (size_t)g * 1600 * QKVN;
  _Float16* oatt  = qkv2g + (size_t)g *  400 * QKVN;
  float*    yt    = (float*)(ws + POS_B + (size_t)g * (QKV_B + OATT_B));
  _Float16* xt0   = (_Float16*)(ws + POS_B + (size_t)g * PB_B);
  _Float16* xt1   = xt0 + (size_t)g * 6400 * C;
  _Float16* xt2   = xt1 + (size_t)g * 1600 * C;
  _Float16* wt    = xt2 + (size_t)g *  400 * C;

  pos_kernel<<<(NH * NT * NT + 255) / 256, 256, 0, stream>>>(rpb, ab, posb);

  const size_t off1 = (size_t)B * C * 6400;
  const size_t off2 = off1 + (size_t)B * C * 1600;

  const int mb0 = (g * 6400 + 127) / 128;
  const int mb1 = (g * 1600 + 127) / 128;
  const int mb2 = (g *  400 + 127) / 128;

  // xpose block ranges
  const int c0 = g * 100;                  // 6400g/64
  const int c1 = c0 + g * 25;              // 1600g/64
  const int c2 = c1 + (g * 400 + 63) / 64;
  const int c3 = c2 + 12;
  const int c4 = c3 + 12;
  const int c5 = c4 + 12;

  for (int b0 = 0; b0 < B; b0 += g) {
    const float* x0g = x0 + (size_t)b0 * C * 6400;
    const float* x1g = x1 + (size_t)b0 * C * 1600;
    const float* x2g = x2 + (size_t)b0 * C * 400;

    xpose_kernel<<<c5, 256, 0, stream>>>(x0g, x1g, x2g, wq0, wq1, wq2,
                                         xt0, xt1, xt2, wt, c0, c1, c2, c3, c4, g);

    qkv_gemm<<<dim3(mb0 + mb1 + mb2, QKVN / 128), 256, 0, stream>>>(
        xt0, xt1, xt2, wt, qkv0g, qkv1g, qkv2g, mb0, mb0 + mb1, g);

    attn_kernel<<<g * NWIN, 256, 0, stream>>>(qkv0g, qkv1g, qkv2g, posb, oatt);

    proj_gemm<<<dim3((g * RPB + 127) / 128, C / 64), 256, 0, stream>>>(oatt, wproj, bproj, yt, g * RPB);

    const int tot0 = g * C * 6400;
    const int tot1 = g * C * 1600;
    const int tot2 = g * C * 400;
    fold_kernel<<<(tot0 + 255) / 256, 256, 0, stream>>>(yt, out + (size_t)b0 * C * 6400,        5, 4, 2, 80, 0,  tot0);
    fold_kernel<<<(tot1 + 255) / 256, 256, 0, stream>>>(yt, out + off1 + (size_t)b0 * C * 1600, 3, 2, 1, 40, 25, tot1);
    fold_kernel<<<(tot2 + 255) / 256, 256, 0, stream>>>(yt, out + off2 + (size_t)b0 * C * 400,  1, 1, 0, 20, 34, tot2);
  }
}